// Round 1
// baseline (421.726 us; speedup 1.0000x reference)
//
#include <hip/hip_runtime.h>

#define KCLS 19
#define CCH 64
#define HW (512*512)
#define NIMG 4

// ws float offsets
#define WS_COUNTS  0      // 19
#define WS_SUMS    32     // [k*64+c], 1216
#define WS_VARSUM  1280   // 19
#define WS_CENTERS 1312   // [k*64+c], 1216
#define WS_SCAL    2560   // 0: loss_dis, 1: loss_reg, 2: n_valid
#define WS_ZERO_BYTES 12288

// ---------------- K1: per-class counts + per-class per-channel sums ----------------
// grid: (512 pixel-chunks of 2048, 4 channel-groups of 16), block 256
__global__ __launch_bounds__(256) void k1_sums(const float* __restrict__ pred,
                                               const int* __restrict__ tgt,
                                               float* __restrict__ ws) {
    const int t = threadIdx.x;
    const int cid = blockIdx.x;          // 512 chunks
    const int n = cid >> 7;              // HW/2048 = 128 chunks per image
    const int hwb = (cid & 127) * 2048;
    const int cg = blockIdx.y;           // channel group, 16 channels each

    __shared__ float hist[16 * 80];      // [c_local][rep*19 + lab], rep in 0..3 (stride 80)
    __shared__ float cnt[80];

    for (int i = t; i < 16 * 80; i += 256) hist[i] = 0.0f;
    if (cg == 0) { if (t < 80) cnt[t] = 0.0f; }

    // labels: 8 pixels per thread (two int4 slots: t and t+256)
    const int4* tg4 = (const int4*)(tgt + n * HW + hwb);
    int4 l0 = tg4[t];
    int4 l1 = tg4[t + 256];
    const int rep = (t & 3) * KCLS;
    int off[8] = { rep + l0.x, rep + l0.y, rep + l0.z, rep + l0.w,
                   rep + l1.x, rep + l1.y, rep + l1.z, rep + l1.w };
    __syncthreads();

    if (cg == 0) {
        #pragma unroll
        for (int p = 0; p < 8; ++p) atomicAdd(&cnt[off[p]], 1.0f);
    }

    for (int cl = 0; cl < 16; ++cl) {
        const int c = cg * 16 + cl;
        const float4* src = (const float4*)(pred + ((size_t)(n * CCH + c)) * HW + hwb);
        float4 v0 = src[t];
        float4 v1 = src[t + 256];
        float* h = &hist[cl * 80];
        atomicAdd(&h[off[0]], v0.x);
        atomicAdd(&h[off[1]], v0.y);
        atomicAdd(&h[off[2]], v0.z);
        atomicAdd(&h[off[3]], v0.w);
        atomicAdd(&h[off[4]], v1.x);
        atomicAdd(&h[off[5]], v1.y);
        atomicAdd(&h[off[6]], v1.z);
        atomicAdd(&h[off[7]], v1.w);
    }
    __syncthreads();

    for (int i = t; i < 16 * KCLS; i += 256) {
        int cl = i / KCLS, k = i % KCLS;
        const float* h = &hist[cl * 80];
        float s = h[k] + h[19 + k] + h[38 + k] + h[57 + k];
        unsafeAtomicAdd(&ws[WS_SUMS + k * CCH + cg * 16 + cl], s);
    }
    if (cg == 0 && t < KCLS) {
        float s = cnt[t] + cnt[19 + t] + cnt[38 + t] + cnt[57 + t];
        unsafeAtomicAdd(&ws[WS_COUNTS + t], s);
    }
}

// ---------------- K2: centers, valid, push (pairwise) + reg terms ----------------
__global__ __launch_bounds__(256) void k2_centers(float* __restrict__ ws) {
    __shared__ float ct[CCH * 20];     // transposed, padded: ct[c*20 + k]
    __shared__ float cntS[KCLS];
    __shared__ float acc[2];           // 0: dis numerator, 1: reg numerator
    const int t = threadIdx.x;
    if (t < KCLS) cntS[t] = ws[WS_COUNTS + t];
    if (t < 2) acc[t] = 0.0f;
    __syncthreads();

    for (int i = t; i < KCLS * CCH; i += 256) {
        int k = i >> 6, c = i & 63;
        float ctr = ws[WS_SUMS + i] / fmaxf(cntS[k], 1.0f);
        ws[WS_CENTERS + i] = ctr;
        ct[c * 20 + k] = ctr;
    }
    __syncthreads();

    for (int p = t; p < KCLS * KCLS; p += 256) {
        int i = p / KCLS, j = p % KCLS;
        if (i != j && cntS[i] > 20.0f && cntS[j] > 20.0f) {
            float sq = 0.0f;
            #pragma unroll 8
            for (int c = 0; c < CCH; ++c) {
                float d = ct[c * 20 + i] - ct[c * 20 + j];
                sq = fmaf(d, d, sq);
            }
            float pd = sqrtf(sq);
            float r = 3.0f - pd;        // 2*DELTA - pd
            if (r > 0.0f) atomicAdd(&acc[0], r * r);
        }
    }
    if (t < KCLS && cntS[t] > 20.0f) {
        float sq = 0.0f;
        #pragma unroll 8
        for (int c = 0; c < CCH; ++c) { float v = ct[c * 20 + t]; sq = fmaf(v, v, sq); }
        atomicAdd(&acc[1], sqrtf(sq));
    }
    __syncthreads();
    if (t == 0) {
        float nv = 0.0f;
        for (int k = 0; k < KCLS; ++k) nv += (cntS[k] > 20.0f) ? 1.0f : 0.0f;
        ws[WS_SCAL + 0] = acc[0] / fmaxf(nv * (nv - 1.0f), 1.0f);
        ws[WS_SCAL + 1] = acc[1] / fmaxf(nv, 1.0f);
        ws[WS_SCAL + 2] = nv;
    }
}

// ---------------- K3: per-pixel pull (variance) term ----------------
// grid: 1024 chunks of 1024 pixels, block 256 (4 px/thread)
__global__ __launch_bounds__(256) void k3_var(const float* __restrict__ pred,
                                              const int* __restrict__ tgt,
                                              float* __restrict__ ws) {
    const int t = threadIdx.x;
    const int cid = blockIdx.x;          // 1024
    const int n = cid >> 8;              // HW/1024 = 256 chunks per image
    const int hwb = (cid & 255) * 1024;

    __shared__ float ct[CCH * 20];       // ct[c*20 + k] -> conflict-free ds_read per c
    __shared__ float varh[80];

    for (int i = t; i < CCH * 20; i += 256) {
        int c = i / 20, k = i % 20;
        ct[i] = (k < KCLS) ? ws[WS_CENTERS + k * CCH + c] : 0.0f;
    }
    if (t < 80) varh[t] = 0.0f;

    const int4 l0 = ((const int4*)(tgt + n * HW + hwb))[t];
    const int lab0 = l0.x, lab1 = l0.y, lab2 = l0.z, lab3 = l0.w;
    float a0 = 0.0f, a1 = 0.0f, a2 = 0.0f, a3 = 0.0f;
    __syncthreads();

    const float* base = pred + (size_t)n * CCH * HW + hwb;
    #pragma unroll 4
    for (int c = 0; c < CCH; ++c) {
        float4 v = ((const float4*)(base + (size_t)c * HW))[t];
        const float* row = &ct[c * 20];
        float m0 = row[lab0], m1 = row[lab1], m2 = row[lab2], m3 = row[lab3];
        float d0 = v.x - m0, d1 = v.y - m1, d2 = v.z - m2, d3 = v.w - m3;
        a0 = fmaf(d0, d0, a0);
        a1 = fmaf(d1, d1, a1);
        a2 = fmaf(d2, d2, a2);
        a3 = fmaf(d3, d3, a3);
    }

    const int rep = (t & 3) * KCLS;
    {
        float d, r;
        d = sqrtf(fmaxf(a0, 1e-12f)); r = d - 0.5f; if (r > 0.0f) atomicAdd(&varh[rep + lab0], r * r);
        d = sqrtf(fmaxf(a1, 1e-12f)); r = d - 0.5f; if (r > 0.0f) atomicAdd(&varh[rep + lab1], r * r);
        d = sqrtf(fmaxf(a2, 1e-12f)); r = d - 0.5f; if (r > 0.0f) atomicAdd(&varh[rep + lab2], r * r);
        d = sqrtf(fmaxf(a3, 1e-12f)); r = d - 0.5f; if (r > 0.0f) atomicAdd(&varh[rep + lab3], r * r);
    }
    __syncthreads();
    if (t < KCLS) {
        float s = varh[t] + varh[19 + t] + varh[38 + t] + varh[57 + t];
        unsafeAtomicAdd(&ws[WS_VARSUM + t], s);
    }
}

// ---------------- K4: final combine ----------------
__global__ void k4_final(const float* __restrict__ ws, float* __restrict__ out) {
    const int t = threadIdx.x;   // 64 threads
    float v = 0.0f;
    if (t < KCLS) {
        float c = ws[WS_COUNTS + t];
        if (c > 20.0f) v = ws[WS_VARSUM + t] / fmaxf(c, 1.0f);
    }
    #pragma unroll
    for (int s = 32; s > 0; s >>= 1) v += __shfl_down(v, s);
    if (t == 0) {
        float nv = ws[WS_SCAL + 2];
        out[0] = v / fmaxf(nv, 1.0f) + ws[WS_SCAL + 0] + 0.001f * ws[WS_SCAL + 1];
    }
}

extern "C" void kernel_launch(void* const* d_in, const int* in_sizes, int n_in,
                              void* d_out, int out_size, void* d_ws, size_t ws_size,
                              hipStream_t stream) {
    const float* pred = (const float*)d_in[0];
    const int* tgt = (const int*)d_in[1];
    float* ws = (float*)d_ws;
    float* out = (float*)d_out;

    hipMemsetAsync(d_ws, 0, WS_ZERO_BYTES, stream);
    hipLaunchKernelGGL(k1_sums, dim3(512, 4), dim3(256), 0, stream, pred, tgt, ws);
    hipLaunchKernelGGL(k2_centers, dim3(1), dim3(256), 0, stream, ws);
    hipLaunchKernelGGL(k3_var, dim3(1024), dim3(256), 0, stream, pred, tgt, ws);
    hipLaunchKernelGGL(k4_final, dim3(1), dim3(64), 0, stream, ws, out);
}

// Round 2
// 421.546 us; speedup vs baseline: 1.0004x; 1.0004x over previous
//
#include <hip/hip_runtime.h>

#define KCLS 19
#define CCH 64
#define HW (512*512)
#define NIMG 4

// ws float offsets
#define WS_COUNTS  0      // 19
#define WS_SUMS    32     // [k*64+c], 1216
#define WS_VARSUM  1280   // 19
#define WS_CENTERS 1312   // [k*64+c], 1216
#define WS_SCAL    2560   // 0: loss_dis, 1: loss_reg, 2: n_valid
#define WS_ZERO_BYTES 12288

// HW float atomic on LDS (ds_add_f32, no CAS loop)
__device__ __forceinline__ void ldsAdd(float* p, float v) { unsafeAtomicAdd(p, v); }

// ---------------- K1: per-class counts + per-class per-channel sums ----------------
// grid: (512 pixel-chunks of 2048, 4 channel-groups of 16), block 256
__global__ __launch_bounds__(256) void k1_sums(const float* __restrict__ pred,
                                               const int* __restrict__ tgt,
                                               float* __restrict__ ws) {
    const int t = threadIdx.x;
    const int cid = blockIdx.x;          // 512 chunks
    const int n = cid >> 7;              // HW/2048 = 128 chunks per image
    const int hwb = (cid & 127) * 2048;
    const int cg = blockIdx.y;           // channel group, 16 channels each

    __shared__ float hist[16 * 80];      // [c_local][rep*19 + lab], rep in 0..3 (stride 80)
    __shared__ float cnt[80];

    for (int i = t; i < 16 * 80; i += 256) hist[i] = 0.0f;
    if (cg == 0) { if (t < 80) cnt[t] = 0.0f; }

    // labels: 8 pixels per thread (two int4 slots: t and t+256)
    const int4* tg4 = (const int4*)(tgt + n * HW + hwb);
    int4 l0 = tg4[t];
    int4 l1 = tg4[t + 256];
    const int rep = (t & 3) * KCLS;
    int off[8] = { rep + l0.x, rep + l0.y, rep + l0.z, rep + l0.w,
                   rep + l1.x, rep + l1.y, rep + l1.z, rep + l1.w };
    __syncthreads();

    if (cg == 0) {
        #pragma unroll
        for (int p = 0; p < 8; ++p) ldsAdd(&cnt[off[p]], 1.0f);
    }

    for (int cl = 0; cl < 16; ++cl) {
        const int c = cg * 16 + cl;
        const float4* src = (const float4*)(pred + ((size_t)(n * CCH + c)) * HW + hwb);
        float4 v0 = src[t];
        float4 v1 = src[t + 256];
        float* h = &hist[cl * 80];
        ldsAdd(&h[off[0]], v0.x);
        ldsAdd(&h[off[1]], v0.y);
        ldsAdd(&h[off[2]], v0.z);
        ldsAdd(&h[off[3]], v0.w);
        ldsAdd(&h[off[4]], v1.x);
        ldsAdd(&h[off[5]], v1.y);
        ldsAdd(&h[off[6]], v1.z);
        ldsAdd(&h[off[7]], v1.w);
    }
    __syncthreads();

    for (int i = t; i < 16 * KCLS; i += 256) {
        int cl = i / KCLS, k = i % KCLS;
        const float* h = &hist[cl * 80];
        float s = h[k] + h[19 + k] + h[38 + k] + h[57 + k];
        unsafeAtomicAdd(&ws[WS_SUMS + k * CCH + cg * 16 + cl], s);
    }
    if (cg == 0 && t < KCLS) {
        float s = cnt[t] + cnt[19 + t] + cnt[38 + t] + cnt[57 + t];
        unsafeAtomicAdd(&ws[WS_COUNTS + t], s);
    }
}

// ---------------- K2: centers, valid, push (pairwise) + reg terms ----------------
__global__ __launch_bounds__(256) void k2_centers(float* __restrict__ ws) {
    __shared__ float ct[CCH * 20];     // transposed, padded: ct[c*20 + k]
    __shared__ float cntS[KCLS];
    __shared__ float acc[2];           // 0: dis numerator, 1: reg numerator
    const int t = threadIdx.x;
    if (t < KCLS) cntS[t] = ws[WS_COUNTS + t];
    if (t < 2) acc[t] = 0.0f;
    __syncthreads();

    for (int i = t; i < KCLS * CCH; i += 256) {
        int k = i >> 6, c = i & 63;
        float ctr = ws[WS_SUMS + i] / fmaxf(cntS[k], 1.0f);
        ws[WS_CENTERS + i] = ctr;
        ct[c * 20 + k] = ctr;
    }
    __syncthreads();

    for (int p = t; p < KCLS * KCLS; p += 256) {
        int i = p / KCLS, j = p % KCLS;
        if (i != j && cntS[i] > 20.0f && cntS[j] > 20.0f) {
            float sq = 0.0f;
            #pragma unroll 8
            for (int c = 0; c < CCH; ++c) {
                float d = ct[c * 20 + i] - ct[c * 20 + j];
                sq = fmaf(d, d, sq);
            }
            float pd = sqrtf(sq);
            float r = 3.0f - pd;        // 2*DELTA - pd
            if (r > 0.0f) ldsAdd(&acc[0], r * r);
        }
    }
    if (t < KCLS && cntS[t] > 20.0f) {
        float sq = 0.0f;
        #pragma unroll 8
        for (int c = 0; c < CCH; ++c) { float v = ct[c * 20 + t]; sq = fmaf(v, v, sq); }
        ldsAdd(&acc[1], sqrtf(sq));
    }
    __syncthreads();
    if (t == 0) {
        float nv = 0.0f;
        for (int k = 0; k < KCLS; ++k) nv += (cntS[k] > 20.0f) ? 1.0f : 0.0f;
        ws[WS_SCAL + 0] = acc[0] / fmaxf(nv * (nv - 1.0f), 1.0f);
        ws[WS_SCAL + 1] = acc[1] / fmaxf(nv, 1.0f);
        ws[WS_SCAL + 2] = nv;
    }
}

// ---------------- K3: per-pixel pull (variance) term ----------------
// grid: 1024 chunks of 1024 pixels, block 256 (4 px/thread)
__global__ __launch_bounds__(256) void k3_var(const float* __restrict__ pred,
                                              const int* __restrict__ tgt,
                                              float* __restrict__ ws) {
    const int t = threadIdx.x;
    const int cid = blockIdx.x;          // 1024
    const int n = cid >> 8;              // HW/1024 = 256 chunks per image
    const int hwb = (cid & 255) * 1024;

    __shared__ float ct[CCH * 20];       // ct[c*20 + k] -> conflict-free ds_read per c
    __shared__ float varh[80];

    for (int i = t; i < CCH * 20; i += 256) {
        int c = i / 20, k = i % 20;
        ct[i] = (k < KCLS) ? ws[WS_CENTERS + k * CCH + c] : 0.0f;
    }
    if (t < 80) varh[t] = 0.0f;

    const int4 l0 = ((const int4*)(tgt + n * HW + hwb))[t];
    const int lab0 = l0.x, lab1 = l0.y, lab2 = l0.z, lab3 = l0.w;
    float a0 = 0.0f, a1 = 0.0f, a2 = 0.0f, a3 = 0.0f;
    __syncthreads();

    const float* base = pred + (size_t)n * CCH * HW + hwb;
    #pragma unroll 4
    for (int c = 0; c < CCH; ++c) {
        float4 v = ((const float4*)(base + (size_t)c * HW))[t];
        const float* row = &ct[c * 20];
        float m0 = row[lab0], m1 = row[lab1], m2 = row[lab2], m3 = row[lab3];
        float d0 = v.x - m0, d1 = v.y - m1, d2 = v.z - m2, d3 = v.w - m3;
        a0 = fmaf(d0, d0, a0);
        a1 = fmaf(d1, d1, a1);
        a2 = fmaf(d2, d2, a2);
        a3 = fmaf(d3, d3, a3);
    }

    const int rep = (t & 3) * KCLS;
    {
        float d, r;
        d = sqrtf(fmaxf(a0, 1e-12f)); r = d - 0.5f; if (r > 0.0f) ldsAdd(&varh[rep + lab0], r * r);
        d = sqrtf(fmaxf(a1, 1e-12f)); r = d - 0.5f; if (r > 0.0f) ldsAdd(&varh[rep + lab1], r * r);
        d = sqrtf(fmaxf(a2, 1e-12f)); r = d - 0.5f; if (r > 0.0f) ldsAdd(&varh[rep + lab2], r * r);
        d = sqrtf(fmaxf(a3, 1e-12f)); r = d - 0.5f; if (r > 0.0f) ldsAdd(&varh[rep + lab3], r * r);
    }
    __syncthreads();
    if (t < KCLS) {
        float s = varh[t] + varh[19 + t] + varh[38 + t] + varh[57 + t];
        unsafeAtomicAdd(&ws[WS_VARSUM + t], s);
    }
}

// ---------------- K4: final combine ----------------
__global__ void k4_final(const float* __restrict__ ws, float* __restrict__ out) {
    const int t = threadIdx.x;   // 64 threads
    float v = 0.0f;
    if (t < KCLS) {
        float c = ws[WS_COUNTS + t];
        if (c > 20.0f) v = ws[WS_VARSUM + t] / fmaxf(c, 1.0f);
    }
    #pragma unroll
    for (int s = 32; s > 0; s >>= 1) v += __shfl_down(v, s);
    if (t == 0) {
        float nv = ws[WS_SCAL + 2];
        out[0] = v / fmaxf(nv, 1.0f) + ws[WS_SCAL + 0] + 0.001f * ws[WS_SCAL + 1];
    }
}

extern "C" void kernel_launch(void* const* d_in, const int* in_sizes, int n_in,
                              void* d_out, int out_size, void* d_ws, size_t ws_size,
                              hipStream_t stream) {
    const float* pred = (const float*)d_in[0];
    const int* tgt = (const int*)d_in[1];
    float* ws = (float*)d_ws;
    float* out = (float*)d_out;

    hipMemsetAsync(d_ws, 0, WS_ZERO_BYTES, stream);
    hipLaunchKernelGGL(k1_sums, dim3(512, 4), dim3(256), 0, stream, pred, tgt, ws);
    hipLaunchKernelGGL(k2_centers, dim3(1), dim3(256), 0, stream, ws);
    hipLaunchKernelGGL(k3_var, dim3(1024), dim3(256), 0, stream, pred, tgt, ws);
    hipLaunchKernelGGL(k4_final, dim3(1), dim3(64), 0, stream, ws, out);
}

// Round 3
// 308.345 us; speedup vs baseline: 1.3677x; 1.3671x over previous
//
#include <hip/hip_runtime.h>

#define KCLS 19
#define CCH 64
#define HW (512*512)
#define NPIX (4*HW)

// K1 geometry
#define CHUNK 16384              // pixels per block (divides HW)
#define NCHUNK (NPIX / CHUNK)    // 64
#define NITER (CHUNK / 256)      // 64 float4-iterations per pass per wave

// ws float offsets
#define WS_COUNTS  0      // 19
#define WS_SUMS    32     // [k*64+c], 1216
#define WS_VARSUM  1280   // 19
#define WS_CENTERS 1312   // [k*64+c], 1216
#define WS_SCAL    2560   // 0: loss_dis, 1: loss_reg, 2: n_valid
#define WS_ZERO_BYTES 12288

__device__ __forceinline__ void ldsAdd(float* p, float v) { unsafeAtomicAdd(p, v); }

// ---------------- K1: per-class counts + per-class per-channel sums ----------------
// grid: (64 chunks, 16 channel-groups), block = 64 threads (1 wave)
// Lane-private replicated bins: bins[j][lane*33 + lab], j = position in float4.
// RMW is plain ds_read/add/ds_write: lanes never share bins -> no atomics.
__global__ __launch_bounds__(64) void k1_sums(const float* __restrict__ pred,
                                              const int* __restrict__ tgt,
                                              float* __restrict__ ws) {
    const int l = threadIdx.x;
    const int chunk = blockIdx.x;
    const int cg = blockIdx.y;
    const int base_px = chunk * CHUNK;
    const int n = base_px / HW;
    const int hwb = base_px - n * HW;

    __shared__ unsigned int labw[CHUNK / 4];     // 16 KB: packed u8 labels, word m = pixels 4m..4m+3
    __shared__ float bins[4][64 * 33];           // 33.8 KB

    // zero the bins we use (k = 0..18 per lane per replica)
    #pragma unroll
    for (int j = 0; j < 4; ++j)
        for (int k = 0; k < KCLS; ++k) bins[j][l * 33 + k] = 0.0f;

    // stage labels packed u8 (reused across the 4 channel passes)
    const int4* tg4 = (const int4*)(tgt + base_px);
    for (int it = 0; it < NITER; ++it) {
        int4 L = tg4[it * 64 + l];
        labw[it * 64 + l] = (unsigned)(L.x & 0xFF) | ((unsigned)(L.y & 0xFF) << 8) |
                            ((unsigned)(L.z & 0xFF) << 16) | ((unsigned)(L.w & 0xFF) << 24);
    }
    __syncthreads();

    float prev = 0.0f;   // per-lane (lanes 0..18): running column total for delta-flush
    const int npass = (cg == 0) ? 5 : 4;         // pass 4 (cg==0 only) = counts (v=1)

    for (int p = 0; p < npass; ++p) {
        const bool cpass = (p == 4);
        const int c = cg * 4 + p;
        const float4* src = (const float4*)(pred + ((size_t)(n * CCH + (cpass ? 0 : c))) * HW + hwb);

        for (int i = 0; i < NITER; ++i) {
            const unsigned lw = labw[i * 64 + l];
            float4 v;
            if (!cpass) v = src[i * 64 + l];
            else { v.x = 1.0f; v.y = 1.0f; v.z = 1.0f; v.w = 1.0f; }
            const int b0 = lw & 31, b1 = (lw >> 8) & 31, b2 = (lw >> 16) & 31, b3 = (lw >> 24) & 31;
            // reads first (replicas are disjoint by construction), then writes
            float h0 = bins[0][l * 33 + b0];
            float h1 = bins[1][l * 33 + b1];
            float h2 = bins[2][l * 33 + b2];
            float h3 = bins[3][l * 33 + b3];
            bins[0][l * 33 + b0] = h0 + v.x;
            bins[1][l * 33 + b1] = h1 + v.y;
            bins[2][l * 33 + b2] = h2 + v.z;
            bins[3][l * 33 + b3] = h3 + v.w;
        }
        __syncthreads();

        // delta flush: 57-lane column sum over 256 rows (4 replicas x 64 lanes)
        float colv = 0.0f;
        const int pp = l / KCLS;                 // 0..2 for l < 57
        const int k = l - pp * KCLS;
        for (int s = 0; s < 86; ++s) {
            int r = pp * 86 + s;
            if (l < 57 && r < 256)
                colv += bins[r >> 6][(r & 63) * 33 + k];
        }
        float s1 = __shfl_down(colv, 19);
        float s2 = __shfl_down(colv, 38);
        float total = colv + s1 + s2;
        if (l < KCLS) {
            float delta = total - prev;
            prev = total;
            if (cpass) unsafeAtomicAdd(&ws[WS_COUNTS + l], delta);
            else       unsafeAtomicAdd(&ws[WS_SUMS + l * CCH + c], delta);
        }
        __syncthreads();
    }
}

// ---------------- K2: centers, valid, push (pairwise) + reg terms ----------------
__global__ __launch_bounds__(256) void k2_centers(float* __restrict__ ws) {
    __shared__ float ct[CCH * 20];     // transposed, padded: ct[c*20 + k]
    __shared__ float cntS[KCLS];
    __shared__ float acc[2];           // 0: dis numerator, 1: reg numerator
    const int t = threadIdx.x;
    if (t < KCLS) cntS[t] = ws[WS_COUNTS + t];
    if (t < 2) acc[t] = 0.0f;
    __syncthreads();

    for (int i = t; i < KCLS * CCH; i += 256) {
        int k = i >> 6, c = i & 63;
        float ctr = ws[WS_SUMS + i] / fmaxf(cntS[k], 1.0f);
        ws[WS_CENTERS + i] = ctr;
        ct[c * 20 + k] = ctr;
    }
    __syncthreads();

    for (int p = t; p < KCLS * KCLS; p += 256) {
        int i = p / KCLS, j = p % KCLS;
        if (i != j && cntS[i] > 20.0f && cntS[j] > 20.0f) {
            float sq = 0.0f;
            #pragma unroll 8
            for (int c = 0; c < CCH; ++c) {
                float d = ct[c * 20 + i] - ct[c * 20 + j];
                sq = fmaf(d, d, sq);
            }
            float pd = sqrtf(sq);
            float r = 3.0f - pd;        // 2*DELTA - pd
            if (r > 0.0f) atomicAdd(&acc[0], r * r);
        }
    }
    if (t < KCLS && cntS[t] > 20.0f) {
        float sq = 0.0f;
        #pragma unroll 8
        for (int c = 0; c < CCH; ++c) { float v = ct[c * 20 + t]; sq = fmaf(v, v, sq); }
        atomicAdd(&acc[1], sqrtf(sq));
    }
    __syncthreads();
    if (t == 0) {
        float nv = 0.0f;
        for (int k = 0; k < KCLS; ++k) nv += (cntS[k] > 20.0f) ? 1.0f : 0.0f;
        ws[WS_SCAL + 0] = acc[0] / fmaxf(nv * (nv - 1.0f), 1.0f);
        ws[WS_SCAL + 1] = acc[1] / fmaxf(nv, 1.0f);
        ws[WS_SCAL + 2] = nv;
    }
}

// ---------------- K3: per-pixel pull (variance) term ----------------
// grid: 1024 chunks of 1024 pixels, block 256 (4 px/thread)
__global__ __launch_bounds__(256) void k3_var(const float* __restrict__ pred,
                                              const int* __restrict__ tgt,
                                              float* __restrict__ ws) {
    const int t = threadIdx.x;
    const int cid = blockIdx.x;          // 1024
    const int n = cid >> 8;              // HW/1024 = 256 chunks per image
    const int hwb = (cid & 255) * 1024;

    __shared__ float ct[CCH * 20];       // ct[c*20 + k]
    __shared__ float varh[80];

    for (int i = t; i < CCH * 20; i += 256) {
        int c = i / 20, k = i % 20;
        ct[i] = (k < KCLS) ? ws[WS_CENTERS + k * CCH + c] : 0.0f;
    }
    if (t < 80) varh[t] = 0.0f;

    const int4 l0 = ((const int4*)(tgt + n * HW + hwb))[t];
    const int lab0 = l0.x, lab1 = l0.y, lab2 = l0.z, lab3 = l0.w;
    float a0 = 0.0f, a1 = 0.0f, a2 = 0.0f, a3 = 0.0f;
    __syncthreads();

    const float* base = pred + (size_t)n * CCH * HW + hwb;
    #pragma unroll 4
    for (int c = 0; c < CCH; ++c) {
        float4 v = ((const float4*)(base + (size_t)c * HW))[t];
        const float* row = &ct[c * 20];
        float m0 = row[lab0], m1 = row[lab1], m2 = row[lab2], m3 = row[lab3];
        float d0 = v.x - m0, d1 = v.y - m1, d2 = v.z - m2, d3 = v.w - m3;
        a0 = fmaf(d0, d0, a0);
        a1 = fmaf(d1, d1, a1);
        a2 = fmaf(d2, d2, a2);
        a3 = fmaf(d3, d3, a3);
    }

    const int rep = (t & 3) * KCLS;
    {
        float d, r;
        d = sqrtf(fmaxf(a0, 1e-12f)); r = d - 0.5f; if (r > 0.0f) ldsAdd(&varh[rep + lab0], r * r);
        d = sqrtf(fmaxf(a1, 1e-12f)); r = d - 0.5f; if (r > 0.0f) ldsAdd(&varh[rep + lab1], r * r);
        d = sqrtf(fmaxf(a2, 1e-12f)); r = d - 0.5f; if (r > 0.0f) ldsAdd(&varh[rep + lab2], r * r);
        d = sqrtf(fmaxf(a3, 1e-12f)); r = d - 0.5f; if (r > 0.0f) ldsAdd(&varh[rep + lab3], r * r);
    }
    __syncthreads();
    if (t < KCLS) {
        float s = varh[t] + varh[19 + t] + varh[38 + t] + varh[57 + t];
        unsafeAtomicAdd(&ws[WS_VARSUM + t], s);
    }
}

// ---------------- K4: final combine ----------------
__global__ void k4_final(const float* __restrict__ ws, float* __restrict__ out) {
    const int t = threadIdx.x;   // 64 threads
    float v = 0.0f;
    if (t < KCLS) {
        float c = ws[WS_COUNTS + t];
        if (c > 20.0f) v = ws[WS_VARSUM + t] / fmaxf(c, 1.0f);
    }
    #pragma unroll
    for (int s = 32; s > 0; s >>= 1) v += __shfl_down(v, s);
    if (t == 0) {
        float nv = ws[WS_SCAL + 2];
        out[0] = v / fmaxf(nv, 1.0f) + ws[WS_SCAL + 0] + 0.001f * ws[WS_SCAL + 1];
    }
}

extern "C" void kernel_launch(void* const* d_in, const int* in_sizes, int n_in,
                              void* d_out, int out_size, void* d_ws, size_t ws_size,
                              hipStream_t stream) {
    const float* pred = (const float*)d_in[0];
    const int* tgt = (const int*)d_in[1];
    float* ws = (float*)d_ws;
    float* out = (float*)d_out;

    hipMemsetAsync(d_ws, 0, WS_ZERO_BYTES, stream);
    hipLaunchKernelGGL(k1_sums, dim3(NCHUNK, 16), dim3(64), 0, stream, pred, tgt, ws);
    hipLaunchKernelGGL(k2_centers, dim3(1), dim3(256), 0, stream, ws);
    hipLaunchKernelGGL(k3_var, dim3(1024), dim3(256), 0, stream, pred, tgt, ws);
    hipLaunchKernelGGL(k4_final, dim3(1), dim3(64), 0, stream, ws, out);
}

// Round 4
// 146.392 us; speedup vs baseline: 2.8808x; 2.1063x over previous
//
#include <hip/hip_runtime.h>

#define KCLS 19
#define CCH 64
#define HW (512*512)
#define NPIX (4*HW)

// K1 geometry: lane = channel
#define NWAVE 4
#define WPX 256                 // pixels per wave
#define BPX (NWAVE * WPX)       // 1024 pixels per block
#define NBLK (NPIX / BPX)       // 1024 blocks

// ws float offsets
#define WS_COUNTS  0      // 19
#define WS_SUMS    32     // [k*64+c], 1216
#define WS_VARSUM  1280   // 19
#define WS_CENTERS 1312   // [k*64+c], 1216
#define WS_SCAL    2560   // 0: loss_dis, 1: loss_reg, 2: n_valid
#define WS_ZERO_BYTES 12288

__device__ __forceinline__ void ldsAdd(float* p, float v) { unsafeAtomicAdd(p, v); }

// ---------------- K1: per-class counts + per-class per-channel sums ----------------
// block 256 (4 waves); wave handles 256 contiguous pixels; lane = channel.
// bins[w][c*21 + k] is lane-private -> plain RMW, no atomics, 2 lanes/bank.
__global__ __launch_bounds__(256) void k1_sums(const float* __restrict__ pred,
                                               const int* __restrict__ tgt,
                                               float* __restrict__ ws) {
    const int t = threadIdx.x;
    const int l = t & 63;            // lane -> channel
    const int w = t >> 6;            // wave id
    const int base_px = blockIdx.x * BPX;
    const int n = base_px / HW;
    const int hwb = base_px - n * HW;

    __shared__ unsigned labw[BPX / 4];        // 1 KB packed u8 labels
    __shared__ float bins[NWAVE][64 * 21];    // 21.5 KB, per-wave per-lane bins
    __shared__ float cnt[16 * 21];            // 1.3 KB, 16-replica count hist

    // zero
    float* bw = bins[w];
    #pragma unroll
    for (int k = 0; k < 21; ++k) bw[l * 21 + k] = 0.0f;
    for (int i = t; i < 16 * 21; i += 256) cnt[i] = 0.0f;
    __syncthreads();

    // stage labels (packed u8) + count histogram via ds_add_f32 (16 replicas)
    {
        int4 L = ((const int4*)(tgt + base_px))[t];
        labw[t] = (unsigned)(L.x & 0xFF) | ((unsigned)(L.y & 0xFF) << 8) |
                  ((unsigned)(L.z & 0xFF) << 16) | ((unsigned)(L.w & 0xFF) << 24);
        float* cr = &cnt[(t & 15) * 21];
        ldsAdd(&cr[L.x & 31], 1.0f);
        ldsAdd(&cr[L.y & 31], 1.0f);
        ldsAdd(&cr[L.z & 31], 1.0f);
        ldsAdd(&cr[L.w & 31], 1.0f);
    }
    __syncthreads();

    // main loop: 64 float4-iterations; per pixel all 64 lanes update own bin row
    const float4* src = (const float4*)(pred + (size_t)(n * CCH + l) * HW + hwb + w * WPX);
    const unsigned* lwp = &labw[w * 64];
    float* br = &bw[l * 21];
    for (int i = 0; i < WPX / 4; ++i) {
        const unsigned lw = lwp[i];          // uniform -> broadcast
        const float4 v = src[i];
        const int b0 = lw & 31, b1 = (lw >> 8) & 31, b2 = (lw >> 16) & 31, b3 = (lw >> 24) & 31;
        br[b0] += v.x;
        br[b1] += v.y;
        br[b2] += v.z;
        br[b3] += v.w;
    }
    __syncthreads();

    // flush: sums (1216 values) and counts (19)
    for (int idx = t; idx < KCLS * CCH; idx += 256) {
        const int k = idx >> 6, c = idx & 63;
        float s = bins[0][c * 21 + k] + bins[1][c * 21 + k] +
                  bins[2][c * 21 + k] + bins[3][c * 21 + k];
        unsafeAtomicAdd(&ws[WS_SUMS + idx], s);
    }
    if (t < KCLS) {
        float s = 0.0f;
        #pragma unroll
        for (int r = 0; r < 16; ++r) s += cnt[r * 21 + t];
        unsafeAtomicAdd(&ws[WS_COUNTS + t], s);
    }
}

// ---------------- K2: centers, valid, push (pairwise) + reg terms ----------------
__global__ __launch_bounds__(256) void k2_centers(float* __restrict__ ws) {
    __shared__ float ct[CCH * 20];     // transposed, padded: ct[c*20 + k]
    __shared__ float cntS[KCLS];
    __shared__ float acc[2];           // 0: dis numerator, 1: reg numerator
    const int t = threadIdx.x;
    if (t < KCLS) cntS[t] = ws[WS_COUNTS + t];
    if (t < 2) acc[t] = 0.0f;
    __syncthreads();

    for (int i = t; i < KCLS * CCH; i += 256) {
        int k = i >> 6, c = i & 63;
        float ctr = ws[WS_SUMS + i] / fmaxf(cntS[k], 1.0f);
        ws[WS_CENTERS + i] = ctr;
        ct[c * 20 + k] = ctr;
    }
    __syncthreads();

    for (int p = t; p < KCLS * KCLS; p += 256) {
        int i = p / KCLS, j = p % KCLS;
        if (i != j && cntS[i] > 20.0f && cntS[j] > 20.0f) {
            float sq = 0.0f;
            #pragma unroll 8
            for (int c = 0; c < CCH; ++c) {
                float d = ct[c * 20 + i] - ct[c * 20 + j];
                sq = fmaf(d, d, sq);
            }
            float pd = sqrtf(sq);
            float r = 3.0f - pd;        // 2*DELTA - pd
            if (r > 0.0f) atomicAdd(&acc[0], r * r);
        }
    }
    if (t < KCLS && cntS[t] > 20.0f) {
        float sq = 0.0f;
        #pragma unroll 8
        for (int c = 0; c < CCH; ++c) { float v = ct[c * 20 + t]; sq = fmaf(v, v, sq); }
        atomicAdd(&acc[1], sqrtf(sq));
    }
    __syncthreads();
    if (t == 0) {
        float nv = 0.0f;
        for (int k = 0; k < KCLS; ++k) nv += (cntS[k] > 20.0f) ? 1.0f : 0.0f;
        ws[WS_SCAL + 0] = acc[0] / fmaxf(nv * (nv - 1.0f), 1.0f);
        ws[WS_SCAL + 1] = acc[1] / fmaxf(nv, 1.0f);
        ws[WS_SCAL + 2] = nv;
    }
}

// ---------------- K3: per-pixel pull (variance) term ----------------
// grid: 1024 chunks of 1024 pixels, block 256 (4 px/thread)
__global__ __launch_bounds__(256) void k3_var(const float* __restrict__ pred,
                                              const int* __restrict__ tgt,
                                              float* __restrict__ ws) {
    const int t = threadIdx.x;
    const int cid = blockIdx.x;          // 1024
    const int n = cid >> 8;              // HW/1024 = 256 chunks per image
    const int hwb = (cid & 255) * 1024;

    __shared__ float ct[CCH * 20];       // ct[c*20 + k]: 19 consecutive banks -> conflict-free
    __shared__ float varh[80];

    for (int i = t; i < CCH * 20; i += 256) {
        int c = i / 20, k = i % 20;
        ct[i] = (k < KCLS) ? ws[WS_CENTERS + k * CCH + c] : 0.0f;
    }
    if (t < 80) varh[t] = 0.0f;

    const int4 l0 = ((const int4*)(tgt + n * HW + hwb))[t];
    const int lab0 = l0.x, lab1 = l0.y, lab2 = l0.z, lab3 = l0.w;
    float a0 = 0.0f, a1 = 0.0f, a2 = 0.0f, a3 = 0.0f;
    __syncthreads();

    const float* base = pred + (size_t)n * CCH * HW + hwb;
    #pragma unroll 4
    for (int c = 0; c < CCH; ++c) {
        float4 v = ((const float4*)(base + (size_t)c * HW))[t];
        const float* row = &ct[c * 20];
        float m0 = row[lab0], m1 = row[lab1], m2 = row[lab2], m3 = row[lab3];
        float d0 = v.x - m0, d1 = v.y - m1, d2 = v.z - m2, d3 = v.w - m3;
        a0 = fmaf(d0, d0, a0);
        a1 = fmaf(d1, d1, a1);
        a2 = fmaf(d2, d2, a2);
        a3 = fmaf(d3, d3, a3);
    }

    const int rep = (t & 3) * KCLS;
    {
        float d, r;
        d = sqrtf(fmaxf(a0, 1e-12f)); r = d - 0.5f; if (r > 0.0f) ldsAdd(&varh[rep + lab0], r * r);
        d = sqrtf(fmaxf(a1, 1e-12f)); r = d - 0.5f; if (r > 0.0f) ldsAdd(&varh[rep + lab1], r * r);
        d = sqrtf(fmaxf(a2, 1e-12f)); r = d - 0.5f; if (r > 0.0f) ldsAdd(&varh[rep + lab2], r * r);
        d = sqrtf(fmaxf(a3, 1e-12f)); r = d - 0.5f; if (r > 0.0f) ldsAdd(&varh[rep + lab3], r * r);
    }
    __syncthreads();
    if (t < KCLS) {
        float s = varh[t] + varh[19 + t] + varh[38 + t] + varh[57 + t];
        unsafeAtomicAdd(&ws[WS_VARSUM + t], s);
    }
}

// ---------------- K4: final combine ----------------
__global__ void k4_final(const float* __restrict__ ws, float* __restrict__ out) {
    const int t = threadIdx.x;   // 64 threads
    float v = 0.0f;
    if (t < KCLS) {
        float c = ws[WS_COUNTS + t];
        if (c > 20.0f) v = ws[WS_VARSUM + t] / fmaxf(c, 1.0f);
    }
    #pragma unroll
    for (int s = 32; s > 0; s >>= 1) v += __shfl_down(v, s);
    if (t == 0) {
        float nv = ws[WS_SCAL + 2];
        out[0] = v / fmaxf(nv, 1.0f) + ws[WS_SCAL + 0] + 0.001f * ws[WS_SCAL + 1];
    }
}

extern "C" void kernel_launch(void* const* d_in, const int* in_sizes, int n_in,
                              void* d_out, int out_size, void* d_ws, size_t ws_size,
                              hipStream_t stream) {
    const float* pred = (const float*)d_in[0];
    const int* tgt = (const int*)d_in[1];
    float* ws = (float*)d_ws;
    float* out = (float*)d_out;

    hipMemsetAsync(d_ws, 0, WS_ZERO_BYTES, stream);
    hipLaunchKernelGGL(k1_sums, dim3(NBLK), dim3(256), 0, stream, pred, tgt, ws);
    hipLaunchKernelGGL(k2_centers, dim3(1), dim3(256), 0, stream, ws);
    hipLaunchKernelGGL(k3_var, dim3(1024), dim3(256), 0, stream, pred, tgt, ws);
    hipLaunchKernelGGL(k4_final, dim3(1), dim3(64), 0, stream, ws, out);
}